// Round 1
// baseline (1956.217 us; speedup 1.0000x reference)
//
#include <hip/hip_runtime.h>

// BiLSTM: B=256, T=512, N=128, H=128. fp32 in/out, bf16 MFMA internally.
//
// ws layout:
//   [0, 512KB)          : W/U bf16 MFMA B-fragments, [arr(4)][gate(4)][kc(4)][tile(8)][lane(64)][8]
//                         arr: 0=Wf 1=Uf 2=Wb 3=Ub
//   [512KB, 512KB+268MB): XW = x@W+b, bf16, swizzled [dir(2)][bblk(16)][s(512)][gate(4)][chunk(4)][lane(64)][8]
//                         (C-layout vals ordered [tile][r] within the lane's 32 values)

typedef short s16x8 __attribute__((ext_vector_type(8)));
typedef float f32x4 __attribute__((ext_vector_type(4)));

#define NT 512      // timesteps
#define FRAG_BYTES 524288

__device__ __forceinline__ unsigned short f2bf(float f) {
  unsigned int u = __float_as_uint(f);
  u += 0x7fffu + ((u >> 16) & 1u);   // RNE
  return (unsigned short)(u >> 16);
}
__device__ __forceinline__ float bflo(unsigned int u) { return __uint_as_float(u << 16); }
__device__ __forceinline__ float bfhi(unsigned int u) { return __uint_as_float(u & 0xffff0000u); }
__device__ __forceinline__ unsigned int packbf2(float a, float b) {
  return (unsigned int)f2bf(a) | ((unsigned int)f2bf(b) << 16);
}
__device__ __forceinline__ float sigm(float x) { return 1.f / (1.f + __expf(-x)); }
__device__ __forceinline__ float tanh_(float x) {
  float xc = fminf(fmaxf(x, -12.f), 12.f);
  float e = __expf(2.f * xc);
  return (e - 1.f) / (e + 1.f);
}

// ---------------------------------------------------------------- kernel 0
// Repack W/U (fp32 [128][512]) into bf16 B-fragment order.
// B-frag (16x16x32): lane holds B[k = (lane>>4)*8 + j][n = lane&15].
__global__ void prep_frags(const float* __restrict__ Wf, const float* __restrict__ Uf,
                           const float* __restrict__ Wb, const float* __restrict__ Ub,
                           unsigned short* __restrict__ frag) {
  int idx = blockIdx.x * 256 + threadIdx.x;          // 0 .. 2^18-1
  int j    = idx & 7;
  int lane = (idx >> 3) & 63;
  int tile = (idx >> 9) & 7;
  int kc   = (idx >> 12) & 3;
  int gate = (idx >> 14) & 3;
  int arr  = (idx >> 16) & 3;
  const float* M = (arr == 0) ? Wf : (arr == 1) ? Uf : (arr == 2) ? Wb : Ub;
  int k   = kc * 32 + (lane >> 4) * 8 + j;
  int col = gate * 128 + tile * 16 + (lane & 15);
  frag[idx] = f2bf(M[k * 512 + col]);
}

// ---------------------------------------------------------------- kernel 1
// XW[dir][bblk][s][gate][...] = x[:, t_in, :] @ W_dir + b_dir  (bf16, swizzled)
// t_in = s (fwd) or 511-s (bwd). One block = (dir, bblk, 16 steps). Wave = gate.
__global__ __launch_bounds__(256, 2) void precompute_xw(
    const float* __restrict__ x, const float* __restrict__ bfw,
    const float* __restrict__ bbw, const unsigned short* __restrict__ frag,
    unsigned short* __restrict__ xw) {
  int bid  = blockIdx.x;
  int sc   = bid & 31;
  int bblk = (bid >> 5) & 15;
  int dir  = bid >> 9;
  int tid  = threadIdx.x;
  int gate = tid >> 6, lane = tid & 63, quad = lane >> 4, m = lane & 15;

  // W fragments for this (dir, gate): 32 frags -> 128 VGPRs
  int arr = dir * 2;  // Wf / Wb
  const unsigned short* fb = frag + ((size_t)(arr * 4 + gate) * 4 * 8 * 64 * 8);
  s16x8 wf[4][8];
#pragma unroll
  for (int kc = 0; kc < 4; kc++)
#pragma unroll
    for (int t = 0; t < 8; t++)
      wf[kc][t] = *(const s16x8*)(fb + ((size_t)(kc * 8 + t) * 64 + lane) * 8);

  const float* bias = dir ? bbw : bfw;
  float bv[8];
#pragma unroll
  for (int t = 0; t < 8; t++) bv[t] = bias[gate * 128 + t * 16 + m];

  for (int s = sc * 16; s < sc * 16 + 16; s++) {
    int t_in = dir ? (NT - 1 - s) : s;
    const float* xp = x + ((size_t)(bblk * 16 + m) * NT + t_in) * 128;
    // A-frags: A[m][k = kc*32 + quad*8 + j] from x (fp32 -> bf16)
    s16x8 a[4];
#pragma unroll
    for (int kc = 0; kc < 4; kc++) {
      float4 v0 = *(const float4*)(xp + kc * 32 + quad * 8);
      float4 v1 = *(const float4*)(xp + kc * 32 + quad * 8 + 4);
      s16x8 av;
      av[0] = (short)f2bf(v0.x); av[1] = (short)f2bf(v0.y);
      av[2] = (short)f2bf(v0.z); av[3] = (short)f2bf(v0.w);
      av[4] = (short)f2bf(v1.x); av[5] = (short)f2bf(v1.y);
      av[6] = (short)f2bf(v1.z); av[7] = (short)f2bf(v1.w);
      a[kc] = av;
    }
    f32x4 acc[8];
#pragma unroll
    for (int t = 0; t < 8; t++) { acc[t][0] = bv[t]; acc[t][1] = bv[t]; acc[t][2] = bv[t]; acc[t][3] = bv[t]; }
#pragma unroll
    for (int kc = 0; kc < 4; kc++)
#pragma unroll
      for (int t = 0; t < 8; t++)
        acc[t] = __builtin_amdgcn_mfma_f32_16x16x32_bf16(a[kc], wf[kc][t], acc[t], 0, 0, 0);
    // pack lane's 32 vals (order [tile][r]) -> 16 uints -> 4 coalesced uint4 stores
    unsigned int u[16];
#pragma unroll
    for (int t = 0; t < 8; t++) {
      u[2 * t]     = packbf2(acc[t][0], acc[t][1]);
      u[2 * t + 1] = packbf2(acc[t][2], acc[t][3]);
    }
    unsigned short* ob = xw + (((size_t)(dir * 16 + bblk) * NT + s) * 4 + gate) * 2048;
#pragma unroll
    for (int i = 0; i < 4; i++) {
      uint4 st; st.x = u[4 * i]; st.y = u[4 * i + 1]; st.z = u[4 * i + 2]; st.w = u[4 * i + 3];
      *(uint4*)(ob + ((size_t)(i * 64 + lane)) * 8) = st;
    }
  }
}

// ---------------------------------------------------------------- kernel 2
// Persistent recurrent kernel. 32 blocks = 2 dirs x 16 batch-blocks (16 rows).
// Wave = gate (i,f,g,o). U in registers. Per step:
//   z = XW[s] (C-init) + h @ U   -> activation -> LDS exchange -> c,h update.
__global__ __launch_bounds__(256, 1) void bilstm_rec(
    const unsigned short* __restrict__ frag, const unsigned short* __restrict__ xw,
    float* __restrict__ out) {
  __shared__ unsigned short h_lds[16][136];  // +8 pad: 2-way-max bank aliasing (free)
  __shared__ float act[4][16][132];          // +4 pad

  int bid = blockIdx.x;
  int bblk = bid & 15, dir = bid >> 4;
  int tid = threadIdx.x;
  int gate = tid >> 6, lane = tid & 63, quad = lane >> 4, m = lane & 15;

  // U fragments: 32 frags -> 128 VGPRs
  int arr = dir * 2 + 1;  // Uf / Ub
  const unsigned short* fb = frag + ((size_t)(arr * 4 + gate) * 4 * 8 * 64 * 8);
  s16x8 uf[4][8];
#pragma unroll
  for (int kc = 0; kc < 4; kc++)
#pragma unroll
    for (int t = 0; t < 8; t++)
      uf[kc][t] = *(const s16x8*)(fb + ((size_t)(kc * 8 + t) * 64 + lane) * 8);

  for (int i = tid; i < 16 * 136; i += 256) ((unsigned short*)h_lds)[i] = 0;

  int erow = tid >> 4, ecol = (tid & 15) * 8;  // elementwise ownership: 8 cols of one row
  float c[8];
#pragma unroll
  for (int j = 0; j < 8; j++) c[j] = 0.f;

  const unsigned short* xwp = xw + ((size_t)(dir * 16 + bblk) * NT * 4 + gate) * 2048;
  uint4 L[4];
#pragma unroll
  for (int i = 0; i < 4; i++) L[i] = *(const uint4*)(xwp + ((size_t)(i * 64 + lane)) * 8);

  float* outp = out + (size_t)(bblk * 16) * NT * 256 + dir * 128;
  __syncthreads();

  for (int s = 0; s < NT; s++) {
    // h A-frags from LDS
    s16x8 a[4];
#pragma unroll
    for (int kc = 0; kc < 4; kc++)
      a[kc] = *(const s16x8*)(&h_lds[m][kc * 32 + quad * 8]);

    // C-init from prefetched XW
    f32x4 acc[8];
    unsigned int* up = (unsigned int*)L;
#pragma unroll
    for (int t = 0; t < 8; t++) {
      unsigned int u0 = up[2 * t], u1 = up[2 * t + 1];
      acc[t][0] = bflo(u0); acc[t][1] = bfhi(u0);
      acc[t][2] = bflo(u1); acc[t][3] = bfhi(u1);
    }
    // prefetch next step's XW (overlaps MFMA + exchange)
    {
      int sn = (s + 1 < NT) ? s + 1 : NT - 1;
      const unsigned short* p = xwp + (size_t)sn * 4 * 2048;
#pragma unroll
      for (int i = 0; i < 4; i++) L[i] = *(const uint4*)(p + ((size_t)(i * 64 + lane)) * 8);
    }

#pragma unroll
    for (int kc = 0; kc < 4; kc++)
#pragma unroll
      for (int t = 0; t < 8; t++)
        acc[t] = __builtin_amdgcn_mfma_f32_16x16x32_bf16(a[kc], uf[kc][t], acc[t], 0, 0, 0);

    // activation (wave-uniform branch) + write to exchange LDS
#pragma unroll
    for (int t = 0; t < 8; t++)
#pragma unroll
      for (int r = 0; r < 4; r++) {
        float z = acc[t][r];
        float v = (gate == 2) ? tanh_(z) : sigm(z);
        act[gate][quad * 4 + r][t * 16 + m] = v;
      }
    __syncthreads();

    // elementwise c/h update: thread owns (erow, ecol..ecol+7)
    float iv[8], fv[8], gv[8], ov[8], hv[8];
    *(float4*)&iv[0] = *(const float4*)&act[0][erow][ecol];
    *(float4*)&iv[4] = *(const float4*)&act[0][erow][ecol + 4];
    *(float4*)&fv[0] = *(const float4*)&act[1][erow][ecol];
    *(float4*)&fv[4] = *(const float4*)&act[1][erow][ecol + 4];
    *(float4*)&gv[0] = *(const float4*)&act[2][erow][ecol];
    *(float4*)&gv[4] = *(const float4*)&act[2][erow][ecol + 4];
    *(float4*)&ov[0] = *(const float4*)&act[3][erow][ecol];
    *(float4*)&ov[4] = *(const float4*)&act[3][erow][ecol + 4];
#pragma unroll
    for (int j = 0; j < 8; j++) {
      c[j] = fv[j] * c[j] + iv[j] * gv[j];
      hv[j] = ov[j] * tanh_(c[j]);
    }
    // h -> LDS (bf16) for next step's A-frags
    uint4 hp;
    hp.x = packbf2(hv[0], hv[1]); hp.y = packbf2(hv[2], hv[3]);
    hp.z = packbf2(hv[4], hv[5]); hp.w = packbf2(hv[6], hv[7]);
    *(uint4*)(&h_lds[erow][ecol]) = hp;
    // h -> global out (fp32)
    float* op = outp + ((size_t)erow * NT + s) * 256 + ecol;
    float4 o0, o1;
    o0.x = hv[0]; o0.y = hv[1]; o0.z = hv[2]; o0.w = hv[3];
    o1.x = hv[4]; o1.y = hv[5]; o1.z = hv[6]; o1.w = hv[7];
    *(float4*)op = o0;
    *(float4*)(op + 4) = o1;
    __syncthreads();
  }
}

extern "C" void kernel_launch(void* const* d_in, const int* in_sizes, int n_in,
                              void* d_out, int out_size, void* d_ws, size_t ws_size,
                              hipStream_t stream) {
  const float* x  = (const float*)d_in[0];
  const float* Wf = (const float*)d_in[1];
  const float* Uf = (const float*)d_in[2];
  const float* bf = (const float*)d_in[3];
  const float* Wb = (const float*)d_in[4];
  const float* Ub = (const float*)d_in[5];
  const float* bb = (const float*)d_in[6];
  float* out = (float*)d_out;

  unsigned short* frag = (unsigned short*)d_ws;
  unsigned short* xw   = (unsigned short*)((char*)d_ws + FRAG_BYTES);

  prep_frags<<<1024, 256, 0, stream>>>(Wf, Uf, Wb, Ub, frag);
  precompute_xw<<<1024, 256, 0, stream>>>(x, bf, bb, frag, xw);
  bilstm_rec<<<32, 256, 0, stream>>>(frag, xw, out);
}

// Round 2
// 1329.340 us; speedup vs baseline: 1.4716x; 1.4716x over previous
//
#include <hip/hip_runtime.h>

// BiLSTM: B=256, T=512, N=128, H=128. fp32 in/out, bf16 MFMA internally.
//
// ws layout:
//   [0, 512KB)   : W/U bf16 MFMA B-fragments [arr(4)][gate(4)][kc(4)][tile(8)][lane(64)][8]
//                  arr: 0=Wf 1=Uf 2=Wb 3=Ub
//   [512KB, +256MiB): XW = x@W+b, bf16, [dir(2)][bblk(16)][s(512)][tile(8)][lane(64)][gate(4)][r(4)]
//                  (per-lane 32B chunk = C-layout init for rec wave `tile`)

typedef short s16x8 __attribute__((ext_vector_type(8)));
typedef float f32x4 __attribute__((ext_vector_type(4)));

#define NT 512
#define FRAG_BYTES 524288

// barrier WITHOUT the compiler's vmcnt(0) drain: LDS ops only.
// Out-stores / XW prefetch stay in flight across it (data deps still get
// compiler-inserted s_waitcnt vmcnt(N) at use sites).
#define LDS_BARRIER() asm volatile("s_waitcnt lgkmcnt(0)\n\ts_barrier" ::: "memory")

__device__ __forceinline__ unsigned short f2bf(float f) {
  unsigned int u = __float_as_uint(f);
  u += 0x7fffu + ((u >> 16) & 1u);   // RNE
  return (unsigned short)(u >> 16);
}
__device__ __forceinline__ float bflo(unsigned int u) { return __uint_as_float(u << 16); }
__device__ __forceinline__ float bfhi(unsigned int u) { return __uint_as_float(u & 0xffff0000u); }
__device__ __forceinline__ unsigned int packbf2(float a, float b) {
  return (unsigned int)f2bf(a) | ((unsigned int)f2bf(b) << 16);
}
__device__ __forceinline__ float sigm(float x) { return 1.f / (1.f + __expf(-x)); }
__device__ __forceinline__ float tanh_(float x) {
  float xc = fminf(fmaxf(x, -12.f), 12.f);
  float e = __expf(2.f * xc);
  return (e - 1.f) / (e + 1.f);
}

// ---------------------------------------------------------------- kernel 0
// Repack W/U (fp32 [128][512]) into bf16 B-fragment order.
// B-frag (16x16x32): lane holds B[k = (lane>>4)*8 + j][n = lane&15].
__global__ void prep_frags(const float* __restrict__ Wf, const float* __restrict__ Uf,
                           const float* __restrict__ Wb, const float* __restrict__ Ub,
                           unsigned short* __restrict__ frag) {
  int idx = blockIdx.x * 256 + threadIdx.x;          // 0 .. 2^18-1
  int j    = idx & 7;
  int lane = (idx >> 3) & 63;
  int tile = (idx >> 9) & 7;
  int kc   = (idx >> 12) & 3;
  int gate = (idx >> 14) & 3;
  int arr  = (idx >> 16) & 3;
  const float* M = (arr == 0) ? Wf : (arr == 1) ? Uf : (arr == 2) ? Wb : Ub;
  int k   = kc * 32 + (lane >> 4) * 8 + j;
  int col = gate * 128 + tile * 16 + (lane & 15);
  frag[idx] = f2bf(M[k * 512 + col]);
}

// ---------------------------------------------------------------- kernel 1
// XW = x@W + b (bf16), stored so rec-wave `tile` loads one 32B chunk/lane.
// One block = (dir, bblk, 16 steps). Wave = gate. x-tile staged via LDS once.
__global__ __launch_bounds__(256, 2) void precompute_xw(
    const float* __restrict__ x, const float* __restrict__ bfw,
    const float* __restrict__ bbw, const unsigned short* __restrict__ frag,
    unsigned short* __restrict__ xw) {
  __shared__ unsigned short xl[16][136];   // 272B row stride: 16B-aligned rows
  int bid  = blockIdx.x;
  int sc   = bid & 31;
  int bblk = (bid >> 5) & 15;
  int dir  = bid >> 9;
  int tid  = threadIdx.x;
  int gate = tid >> 6, lane = tid & 63, quad = lane >> 4, m = lane & 15;

  // W fragments for this (dir, gate): 32 frags -> 128 VGPRs
  const unsigned short* fb = frag + ((size_t)((dir * 2) * 4 + gate) * 4 * 8 * 64 * 8);
  s16x8 wf[4][8];
#pragma unroll
  for (int kc = 0; kc < 4; kc++)
#pragma unroll
    for (int t = 0; t < 8; t++)
      wf[kc][t] = *(const s16x8*)(fb + ((size_t)(kc * 8 + t) * 64 + lane) * 8);

  const float* bias = dir ? bbw : bfw;
  float bv[8];
#pragma unroll
  for (int t = 0; t < 8; t++) bv[t] = bias[gate * 128 + t * 16 + m];

  int srow = tid >> 4, sc8 = (tid & 15) * 8;   // staging ownership
  for (int s = sc * 16; s < sc * 16 + 16; s++) {
    int t_in = dir ? (NT - 1 - s) : s;
    const float* xp = x + ((size_t)(bblk * 16 + srow) * NT + t_in) * 128 + sc8;
    float4 v0 = *(const float4*)xp;
    float4 v1 = *(const float4*)(xp + 4);
    uint4 pk;
    pk.x = packbf2(v0.x, v0.y); pk.y = packbf2(v0.z, v0.w);
    pk.z = packbf2(v1.x, v1.y); pk.w = packbf2(v1.z, v1.w);
    __syncthreads();                       // WAR vs previous step's frag reads
    *(uint4*)(&xl[srow][sc8]) = pk;
    __syncthreads();

    s16x8 a[4];
#pragma unroll
    for (int kc = 0; kc < 4; kc++)
      a[kc] = *(const s16x8*)(&xl[m][kc * 32 + quad * 8]);

    f32x4 acc[8];
#pragma unroll
    for (int t = 0; t < 8; t++) { acc[t][0] = bv[t]; acc[t][1] = bv[t]; acc[t][2] = bv[t]; acc[t][3] = bv[t]; }
#pragma unroll
    for (int kc = 0; kc < 4; kc++)
#pragma unroll
      for (int t = 0; t < 8; t++)
        acc[t] = __builtin_amdgcn_mfma_f32_16x16x32_bf16(a[kc], wf[kc][t], acc[t], 0, 0, 0);

    unsigned short* ob = xw + ((size_t)(dir * 16 + bblk) * NT + s) * 8192;
#pragma unroll
    for (int t = 0; t < 8; t++) {
      uint2 st;
      st.x = packbf2(acc[t][0], acc[t][1]);
      st.y = packbf2(acc[t][2], acc[t][3]);
      *(uint2*)(ob + (size_t)(t * 64 + lane) * 16 + gate * 4) = st;
    }
  }
}

// ---------------------------------------------------------------- kernel 2
// Persistent recurrent kernel. 32 blocks = 2 dirs x 16 batch-blocks (16 rows).
// 8 waves; wave = column-slice tc (16 cols x all 4 gates) -> i,f,g,o for the
// lane's slice stay in-register: no act exchange. One LDS barrier per step
// (double-buffered h), and it skips the vmcnt drain (LDS_BARRIER).
__global__ __launch_bounds__(512, 2) void bilstm_rec(
    const unsigned short* __restrict__ frag, const unsigned short* __restrict__ xw,
    float* __restrict__ out) {
  __shared__ unsigned short hl[2][16][136];

  int bid = blockIdx.x;
  int bblk = bid & 15, dir = bid >> 4;
  int tid = threadIdx.x;
  int tc = tid >> 6, lane = tid & 63, quad = lane >> 4, m = lane & 15;

  // U fragments for (dir, all gates, tile tc): 16 frags -> 64 VGPRs
  int arr = dir * 2 + 1;  // Uf / Ub
  s16x8 uf[4][4];         // [gate][kc]
#pragma unroll
  for (int g = 0; g < 4; g++)
#pragma unroll
    for (int kc = 0; kc < 4; kc++)
      uf[g][kc] = *(const s16x8*)(frag +
          ((size_t)(((arr * 4 + g) * 4 + kc) * 8 + tc) * 64 + lane) * 8);

  for (int i = tid; i < 2 * 16 * 136; i += 512) ((unsigned short*)hl)[i] = 0;

  float c[4] = {0.f, 0.f, 0.f, 0.f};

  const unsigned short* xwp = xw + (size_t)(dir * 16 + bblk) * NT * 8192
                                 + (size_t)(tc * 64 + lane) * 16;
  uint4 L[2][2];
  L[0][0] = *(const uint4*)(xwp);
  L[0][1] = *(const uint4*)(xwp + 8);

  float* outp = out + (size_t)(bblk * 16) * NT * 256 + dir * 128 + tc * 16 + m;
  __syncthreads();

  for (int s = 0; s < NT; s++) {
    int cb = s & 1, nb = cb ^ 1;
    // prefetch next step's XW (in flight across the barrier)
    {
      int sn = (s + 1 < NT) ? s + 1 : NT - 1;
      const unsigned short* p = xwp + (size_t)sn * 8192;
      L[nb][0] = *(const uint4*)(p);
      L[nb][1] = *(const uint4*)(p + 8);
    }
    // h A-frags from LDS buffer cb
    s16x8 a[4];
#pragma unroll
    for (int kc = 0; kc < 4; kc++)
      a[kc] = *(const s16x8*)(&hl[cb][m][kc * 32 + quad * 8]);

    // C-init from prefetched XW: chunk shorts = [g(4)][r(4)]
    f32x4 acc[4];
    uint4 A0 = L[cb][0], A1 = L[cb][1];
    acc[0][0] = bflo(A0.x); acc[0][1] = bfhi(A0.x); acc[0][2] = bflo(A0.y); acc[0][3] = bfhi(A0.y);
    acc[1][0] = bflo(A0.z); acc[1][1] = bfhi(A0.z); acc[1][2] = bflo(A0.w); acc[1][3] = bfhi(A0.w);
    acc[2][0] = bflo(A1.x); acc[2][1] = bfhi(A1.x); acc[2][2] = bflo(A1.y); acc[2][3] = bfhi(A1.y);
    acc[3][0] = bflo(A1.z); acc[3][1] = bfhi(A1.z); acc[3][2] = bflo(A1.w); acc[3][3] = bfhi(A1.w);

#pragma unroll
    for (int kc = 0; kc < 4; kc++)
#pragma unroll
      for (int g = 0; g < 4; g++)
        acc[g] = __builtin_amdgcn_mfma_f32_16x16x32_bf16(a[kc], uf[g][kc], acc[g], 0, 0, 0);

    // in-register activations + c/h update (lane owns rows quad*4+r, col tc*16+m)
    float hv[4];
#pragma unroll
    for (int r = 0; r < 4; r++) {
      float iv = sigm(acc[0][r]);
      float fv = sigm(acc[1][r]);
      float gv = tanh_(acc[2][r]);
      float ov = sigm(acc[3][r]);
      c[r] = fv * c[r] + iv * gv;
      hv[r] = ov * tanh_(c[r]);
    }
    // h -> LDS buffer nb (bf16) for next step's A-frags
#pragma unroll
    for (int r = 0; r < 4; r++)
      hl[nb][quad * 4 + r][tc * 16 + m] = f2bf(hv[r]);
    // h -> global out (fp32)
#pragma unroll
    for (int r = 0; r < 4; r++)
      outp[((size_t)(quad * 4 + r) * NT + s) * 256] = hv[r];

    LDS_BARRIER();
  }
}

extern "C" void kernel_launch(void* const* d_in, const int* in_sizes, int n_in,
                              void* d_out, int out_size, void* d_ws, size_t ws_size,
                              hipStream_t stream) {
  const float* x  = (const float*)d_in[0];
  const float* Wf = (const float*)d_in[1];
  const float* Uf = (const float*)d_in[2];
  const float* bf = (const float*)d_in[3];
  const float* Wb = (const float*)d_in[4];
  const float* Ub = (const float*)d_in[5];
  const float* bb = (const float*)d_in[6];
  float* out = (float*)d_out;

  unsigned short* frag = (unsigned short*)d_ws;
  unsigned short* xw   = (unsigned short*)((char*)d_ws + FRAG_BYTES);

  prep_frags<<<1024, 256, 0, stream>>>(Wf, Uf, Wb, Ub, frag);
  precompute_xw<<<1024, 256, 0, stream>>>(x, bf, bb, frag, xw);
  bilstm_rec<<<32, 512, 0, stream>>>(frag, xw, out);
}

// Round 3
// 748.832 us; speedup vs baseline: 2.6124x; 1.7752x over previous
//
#include <hip/hip_runtime.h>

// BiLSTM: B=256, T=512, N=128, H=128. fp32 in/out, bf16 MFMA internally.
// Fused: z = [x_t | h] @ [W;U] + b computed per step (no XW intermediate).
//
// ws layout:
//   [0, 512KB): combined WU bf16 MFMA B-fragments
//               [dir(2)][gate(4)][kc(8)][tile(8)][lane(64)][8]
//               kc<4 -> W rows kc*32.., kc>=4 -> U rows (kc-4)*32..

typedef short s16x8 __attribute__((ext_vector_type(8)));
typedef float f32x4 __attribute__((ext_vector_type(4)));

#define NT 512
#define LDSROW 272   // bf16 per LDS row: 256 data + 16 pad (136 dwords = 8 mod 32 banks)

// Barrier with LDS-only drain (no vmcnt(0) at source level): out-stores and
// the x prefetch stay in flight; data deps get compiler-inserted vmcnt(N).
#define LDS_BARRIER() asm volatile("s_waitcnt lgkmcnt(0)\n\ts_barrier" ::: "memory")

__device__ __forceinline__ unsigned short f2bf(float f) {
  unsigned int u = __float_as_uint(f);
  u += 0x7fffu + ((u >> 16) & 1u);   // RNE
  return (unsigned short)(u >> 16);
}
__device__ __forceinline__ unsigned int packbf2(float a, float b) {
  return (unsigned int)f2bf(a) | ((unsigned int)f2bf(b) << 16);
}
__device__ __forceinline__ float sigm(float x) {
  return __builtin_amdgcn_rcpf(1.f + __expf(-x));      // 2 trans, no div-fixup
}
__device__ __forceinline__ float tanh_(float x) {
  float xc = fminf(fmaxf(x, -12.f), 12.f);
  return 1.f - 2.f * __builtin_amdgcn_rcpf(1.f + __expf(2.f * xc));
}

// ---------------------------------------------------------------- kernel 0
// Repack [W;U] (fp32 [128][512] each) into bf16 B-fragment order, K=256.
// B-frag (16x16x32): lane holds B[k = (lane>>4)*8 + j][n = lane&15].
__global__ void prep_frags(const float* __restrict__ Wf, const float* __restrict__ Uf,
                           const float* __restrict__ Wb, const float* __restrict__ Ub,
                           unsigned short* __restrict__ frag) {
  int idx = blockIdx.x * 256 + threadIdx.x;          // 0 .. 2^18-1
  int j    = idx & 7;
  int lane = (idx >> 3) & 63;
  int tile = (idx >> 9) & 7;
  int kc   = (idx >> 12) & 7;
  int gate = (idx >> 15) & 3;
  int dir  = (idx >> 17) & 1;
  const float* M = (kc < 4) ? (dir ? Wb : Wf) : (dir ? Ub : Uf);
  int k   = (kc & 3) * 32 + (lane >> 4) * 8 + j;
  int col = gate * 128 + tile * 16 + (lane & 15);
  frag[idx] = f2bf(M[k * 512 + col]);
}

// ---------------------------------------------------------------- kernel 1
// Persistent fused recurrent kernel. 32 blocks = 2 dirs x 16 batch-blocks
// (16 rows each). 8 waves; wave = column-slice tc (16 cols x all 4 gates),
// so i,f,g,o stay in-register. One LDS barrier per step, double-buffered
// [x_t | h] tile in LDS, WU fragments in registers (128 VGPRs).
__global__ __launch_bounds__(512, 2) void bilstm_rec(
    const unsigned short* __restrict__ frag, const float* __restrict__ x,
    const float* __restrict__ bfw, const float* __restrict__ bbw,
    float* __restrict__ out) {
  __shared__ unsigned short xh[2][16][LDSROW];   // cols 0..127 = x_t, 128..255 = h

  int bid = blockIdx.x;
  int bblk = bid & 15, dir = bid >> 4;
  int tid = threadIdx.x;
  int tc = tid >> 6, lane = tid & 63, quad = lane >> 4, m = lane & 15;

  // WU fragments for (dir, all gates, tile tc): 32 frags -> 128 VGPRs
  s16x8 wu[4][8];   // [gate][kc]
#pragma unroll
  for (int g = 0; g < 4; g++)
#pragma unroll
    for (int kc = 0; kc < 8; kc++)
      wu[g][kc] = *(const s16x8*)(frag +
          ((((size_t)(dir * 4 + g) * 8 + kc) * 8 + tc) * 64 + lane) * 8);

  const float* bias = dir ? bbw : bfw;
  float bv[4];
#pragma unroll
  for (int g = 0; g < 4; g++) bv[g] = bias[g * 128 + tc * 16 + m];

  // x staging ownership: thread -> (row, 4 cols)
  int srow = tid >> 5, scol = (tid & 31) * 4;
  const float* xbase = x + ((size_t)(bblk * 16 + srow) * NT) * 128 + scol;

  // prologue: stage x(t_in(0)) into xh[0], zero h-part of xh[0]
  {
    int t0 = dir ? (NT - 1) : 0;
    float4 v = *(const float4*)(xbase + (size_t)t0 * 128);
    uint2 pk; pk.x = packbf2(v.x, v.y); pk.y = packbf2(v.z, v.w);
    *(uint2*)(&xh[0][srow][scol]) = pk;
  }
  for (int i = tid; i < 16 * 64; i += 512) {
    int row = i >> 6, cc = i & 63;
    *(unsigned int*)(&xh[0][row][128 + cc * 2]) = 0;
  }
  __syncthreads();

  float c4[4] = {0.f, 0.f, 0.f, 0.f};
  float* outp = out + (size_t)(bblk * 16) * NT * 256 + dir * 128 + tc * 16 + m;

  for (int s = 0; s < NT; s++) {
    int cb = s & 1, nb = cb ^ 1;

    // x prefetch for step s+1 (issued first: latency overlaps whole body)
    int sn = (s + 1 < NT) ? (s + 1) : (NT - 1);
    int tn = dir ? (NT - 1 - sn) : sn;
    float4 vx = *(const float4*)(xbase + (size_t)tn * 128);

    // A-frags [x_t | h] from LDS buffer cb (bank-balanced ds_read_b128 x8)
    s16x8 a[8];
#pragma unroll
    for (int kc = 0; kc < 8; kc++)
      a[kc] = *(const s16x8*)(&xh[cb][m][kc * 32 + quad * 8]);

    f32x4 acc[4];
#pragma unroll
    for (int g = 0; g < 4; g++) {
      acc[g][0] = bv[g]; acc[g][1] = bv[g]; acc[g][2] = bv[g]; acc[g][3] = bv[g];
    }
#pragma unroll
    for (int kc = 0; kc < 8; kc++)
#pragma unroll
      for (int g = 0; g < 4; g++)
        acc[g] = __builtin_amdgcn_mfma_f32_16x16x32_bf16(a[kc], wu[g][kc], acc[g], 0, 0, 0);

    // in-register activations + c/h update (lane owns rows quad*4+r, col tc*16+m)
    float hv[4];
#pragma unroll
    for (int r = 0; r < 4; r++) {
      float iv = sigm(acc[0][r]);
      float fv = sigm(acc[1][r]);
      float gv = tanh_(acc[2][r]);
      float ov = sigm(acc[3][r]);
      c4[r] = fv * c4[r] + iv * gv;
      hv[r] = ov * tanh_(c4[r]);
    }

    // LDS writes first (they gate the barrier's lgkmcnt drain)
#pragma unroll
    for (int r = 0; r < 4; r++)
      xh[nb][quad * 4 + r][128 + tc * 16 + m] = f2bf(hv[r]);
    {
      uint2 pk; pk.x = packbf2(vx.x, vx.y); pk.y = packbf2(vx.z, vx.w);
      *(uint2*)(&xh[nb][srow][scol]) = pk;
    }

    // global out stores last (can stay in flight across the barrier)
#pragma unroll
    for (int r = 0; r < 4; r++)
      outp[((size_t)(quad * 4 + r) * NT + s) * 256] = hv[r];

    LDS_BARRIER();
  }
}

extern "C" void kernel_launch(void* const* d_in, const int* in_sizes, int n_in,
                              void* d_out, int out_size, void* d_ws, size_t ws_size,
                              hipStream_t stream) {
  const float* x  = (const float*)d_in[0];
  const float* Wf = (const float*)d_in[1];
  const float* Uf = (const float*)d_in[2];
  const float* bf = (const float*)d_in[3];
  const float* Wb = (const float*)d_in[4];
  const float* Ub = (const float*)d_in[5];
  const float* bb = (const float*)d_in[6];
  float* out = (float*)d_out;

  unsigned short* frag = (unsigned short*)d_ws;

  prep_frags<<<1024, 256, 0, stream>>>(Wf, Uf, Wb, Ub, frag);
  bilstm_rec<<<32, 512, 0, stream>>>(frag, x, bf, bb, out);
}